// Round 16
// baseline (55.251 us; speedup 1.0000x reference)
//
#include <hip/hip_runtime.h>
#include <hip/hip_bf16.h>

// Problem constants (match reference)
#define T_TOK 8192
#define DDIM  1024
#define HDIM  512
#define NE    8
#define TPE   (T_TOK / NE)   // 1024 tokens per expert (static partition per reference)

typedef __attribute__((ext_vector_type(4))) float floatx4;
typedef __attribute__((ext_vector_type(8))) short bf16x8;

#define SBAR() __builtin_amdgcn_sched_barrier(0)
#define BARRIER() __builtin_amdgcn_s_barrier()
#define WAIT_LGKM0() do { asm volatile("s_waitcnt lgkmcnt(0)" ::: "memory"); SBAR(); } while (0)

__device__ __forceinline__ unsigned short f2bf(float f) {
    union { float f; unsigned int u; } v;
    v.f = f;
    unsigned int u = v.u;
    unsigned int r = u + 0x7FFFu + ((u >> 16) & 1u);  // RNE
    return (unsigned short)(r >> 16);
}

// packed f32x2 -> bf16x2 (RNE), single instruction
__device__ __forceinline__ unsigned int cvt_pk_bf16(float lo, float hi) {
    unsigned int r;
    asm("v_cvt_pk_bf16_f32 %0, %1, %2" : "=v"(r) : "v"(lo), "v"(hi));
    return r;
}

// async global -> LDS, 16 bytes per lane (dest must be linear: base + lane*16)
__device__ __forceinline__ void gld_lds16(const void* g, void* l) {
    __builtin_amdgcn_global_load_lds(
        (const __attribute__((address_space(1))) unsigned int*)g,
        (__attribute__((address_space(3))) unsigned int*)l, 16, 0, 0);
}

// ---------------------------------------------------------------------------
// Kernel 0 (streaming): X*scale -> bf16 only (48 MB round trip).
// ---------------------------------------------------------------------------
__global__ __launch_bounds__(256)
void convert_x_kernel(const float* __restrict__ X, const float* __restrict__ S,
                      unsigned short* __restrict__ Xb)
{
    const int NTX = (T_TOK * DDIM) / 4;            // 2,097,152 float4 chunks
    const int stride = gridDim.x * blockDim.x;
    for (int i = blockIdx.x * blockDim.x + threadIdx.x; i < NTX; i += stride) {
        int row = i >> 8;            // D/4 = 256 chunks per row
        int c4  = i & 255;
        float4 v = reinterpret_cast<const float4*>(X)[i];
        float sc = S[row * (DDIM / 32) + (c4 >> 3)];
        ushort4 b;
        b.x = f2bf(v.x * sc); b.y = f2bf(v.y * sc);
        b.z = f2bf(v.z * sc); b.w = f2bf(v.w * sc);
        reinterpret_cast<ushort4*>(Xb)[i] = b;
    }
}

// XCD-aware swizzles (nwg % 8 == 0 -> bijective)
__device__ __forceinline__ int xcd_swizzle_512(int raw) {
    return (raw & 7) * 64 + (raw >> 3);
}
__device__ __forceinline__ int xcd_swizzle_256(int raw) {
    return (raw & 7) * 32 + (raw >> 3);
}

// LDS tile layout: [rows][8 slots of 16B]. Bank-conflict swizzle (T2/G21):
//   phys 16B-slot = logical_slot ^ (row & 7)
//   - gld_lds path: LDS dest LINEAR, global SOURCE slot pre-permuted.
//   - reg-staged path: ds_write directly to the swizzled slot.
//   - ds_read applies the same XOR.

// ---------------------------------------------------------------------------
// Kernel 1: h = silu(Xb W1^T) * (Xb W3^T).  BM=256, BN=64, BK=64, 512 thr.
// ROUND-16 CHANGE: m201-cadence 4-phase K-step (T3+T4+T5). Each K-step t:
//   P0: ds_read a/b1(ks0)      | STAGEA(t+1)   | bar | lgkm0 | prio1 8xMFMA h1 | bar
//   P1: ds_read b3(ks0)        | LOADB(t+2)    | bar | lgkm0 | prio1 8xMFMA h3 | bar
//   P2: ds_read a/b1(ks1)      | vmcnt(8)+WRITEB(t+1) | bar | lgkm0 | prio1 8xMFMA h1 | bar
//   P3: ds_read b3(ks1)        | vmcnt(4)      | bar | lgkm0 | prio1 8xMFMA h3 | bar
// FIFO ledger (per wave, 4 VM ops per slice): vmcnt(8) at P2 drains exactly
// LOADB(t+1) (STAGEA(t+1)+LOADB(t+2) remain); vmcnt(4) at P3 drains
// STAGEA(t+1), leaving LOADB(t+2) airborne across the K-step boundary.
// sA dbuf 64 KB + sB dbuf 32 KB = 96 KB -> 1 block/CU, 8 waves (m201 also 1/CU).
// ---------------------------------------------------------------------------
__global__ __launch_bounds__(512, 2)
void gemm1_silu_kernel(const unsigned short* __restrict__ Xb,
                       const float* __restrict__ W13,
                       __hip_bfloat16* __restrict__ Hout)
{
    const int bid = xcd_swizzle_256(blockIdx.x);
    const int e  = bid >> 5;
    const int mt = (bid >> 3) & 3;    // token tile (256 rows)
    const int nt = bid & 7;           // h tile (64 cols)
    const int tok0 = e * TPE + mt * 256;
    const float* __restrict__ We = W13 + (size_t)e * (2 * HDIM) * DDIM;

    __shared__ __hip_bfloat16 sA[2][256][64];   // 64 KB
    __shared__ __hip_bfloat16 sB[2][128][64];   // 32 KB

    const int tid  = threadIdx.x;
    const int lane = tid & 63;
    const int wave = tid >> 6;   // 0..7
    const int wr = wave >> 1;    // 0..3 (M quarter: 64 rows)
    const int wc = wave & 1;     // 0..1 (N: 32 cols each)
    const int lr = lane & 15;
    const int sw0 = ((lane >> 4) ^ (lane & 7));

    floatx4 acc1[4][2] = {};
    floatx4 acc3[4][2] = {};

    // A staging: 256x64 bf16 = 2048 x 16B chunks / 512 thr = 4 each
    const int srowA = tid >> 3;                          // 0..63
    const int dcolA = (tid & 7) * 8;                     // LDS linear dest
    const int gcolA = ((tid & 7) ^ (srowA & 7)) * 8;     // pre-swizzled source
    // B load: 128 rows x 16 float4 / 512 thr = 4 each
    const int srowB = tid >> 4;                          // 0..31
    const int f4    = tid & 15;                          // float4 slot in row
    const int bcol  = f4 * 4;                            // fp32 col

    float4 rB0[4], rB1[4];

    auto LOADB = [&](int kk, float4* rB) {   // 4 VM ops, fp32 W13 (w1|w3 rows)
        const int k0 = kk * 64;
        #pragma unroll
        for (int j = 0; j < 4; ++j) {
            int row = srowB + j * 32;        // 0..127; row&7 const under +32
            int wrow = (j < 2) ? (nt * 64 + row)                 // w1 rows
                               : (HDIM + nt * 64 + (row - 64));  // w3 rows
            rB[j] = *reinterpret_cast<const float4*>(
                        &We[(size_t)wrow * DDIM + k0 + bcol]);
        }
    };
    auto STAGEA = [&](int kk, int buf) {     // 4 VM ops (gld_lds)
        const int k0 = kk * 64;
        #pragma unroll
        for (int j = 0; j < 4; ++j) {
            int row = srowA + j * 64;        // row&7 const under +64
            gld_lds16(&Xb[(size_t)(tok0 + row) * DDIM + k0 + gcolA],
                      &sA[buf][row][dcolA]);
        }
    };
    auto WRITEB = [&](int buf, const float4* rB) {   // cvt + swizzled ds_write_b64
        #pragma unroll
        for (int j = 0; j < 4; ++j) {
            int row = srowB + j * 32;
            uint2 w;
            w.x = cvt_pk_bf16(rB[j].x, rB[j].y);
            w.y = cvt_pk_bf16(rB[j].z, rB[j].w);
            char* base = reinterpret_cast<char*>(&sB[buf][row][0]);
            int off = (((f4 >> 1) ^ (row & 7)) << 4) + ((f4 & 1) << 3);
            *reinterpret_cast<uint2*>(base + off) = w;
        }
    };
    auto DS_A = [&](int buf, int ks, bf16x8* a) {
        const int rc = (sw0 ^ (ks << 2)) << 3;
        #pragma unroll
        for (int m = 0; m < 4; ++m)
            a[m] = *reinterpret_cast<const bf16x8*>(&sA[buf][wr * 64 + m * 16 + lr][rc]);
    };
    auto DS_B1 = [&](int buf, int ks, bf16x8* b) {
        const int rc = (sw0 ^ (ks << 2)) << 3;
        #pragma unroll
        for (int n = 0; n < 2; ++n)
            b[n] = *reinterpret_cast<const bf16x8*>(&sB[buf][wc * 32 + n * 16 + lr][rc]);
    };
    auto DS_B3 = [&](int buf, int ks, bf16x8* b) {
        const int rc = (sw0 ^ (ks << 2)) << 3;
        #pragma unroll
        for (int n = 0; n < 2; ++n)
            b[n] = *reinterpret_cast<const bf16x8*>(&sB[buf][64 + wc * 32 + n * 16 + lr][rc]);
    };
    auto MFMA1 = [&](bf16x8* a, bf16x8* b) {
        #pragma unroll
        for (int m = 0; m < 4; ++m)
            #pragma unroll
            for (int n = 0; n < 2; ++n)
                acc1[m][n] = __builtin_amdgcn_mfma_f32_16x16x32_bf16(a[m], b[n], acc1[m][n], 0, 0, 0);
    };
    auto MFMA3 = [&](bf16x8* a, bf16x8* b) {
        #pragma unroll
        for (int m = 0; m < 4; ++m)
            #pragma unroll
            for (int n = 0; n < 2; ++n)
                acc3[m][n] = __builtin_amdgcn_mfma_f32_16x16x32_bf16(a[m], b[n], acc3[m][n], 0, 0, 0);
    };

    bf16x8 a[4], a2[4], b1[2], b3[2];

    // ---- prologue: VM order [LOADB(0) 4][STAGEA(0) 4][LOADB(1) 4]
    LOADB(0, rB0);  SBAR();
    STAGEA(0, 0);   SBAR();
    LOADB(1, rB1);  SBAR();
    asm volatile("s_waitcnt vmcnt(8)" ::: "memory");   // LOADB(0) done
    SBAR();
    WRITEB(0, rB0); SBAR();
    asm volatile("s_waitcnt vmcnt(4) lgkmcnt(0)" ::: "memory"); // STAGEA(0)+writes
    SBAR();
    BARRIER();
    // steady entry: outstanding VM = LOADB(1) [4]

    // ---- steady K-steps t = 0..13 (even/odd unrolled for static rB names)
    for (int t = 0; t < DDIM / 64 - 2; t += 2) {        // t = 0,2,...,12
        // ======== K-step t (buf 0): WRITEB->sB[1] from rB1; LOADB(t+2)->rB0
        // P0
        DS_A(0, 0, a); DS_B1(0, 0, b1); SBAR();
        STAGEA(t + 1, 1); SBAR();
        BARRIER(); WAIT_LGKM0();
        __builtin_amdgcn_s_setprio(1); MFMA1(a, b1); __builtin_amdgcn_s_setprio(0);
        SBAR(); BARRIER();
        // P1
        DS_B3(0, 0, b3); SBAR();
        LOADB(t + 2, rB0); SBAR();
        BARRIER(); WAIT_LGKM0();
        __builtin_amdgcn_s_setprio(1); MFMA3(a, b3); __builtin_amdgcn_s_setprio(0);
        SBAR(); BARRIER();
        // P2
        DS_A(0, 1, a2); DS_B1(0, 1, b1); SBAR();
        asm volatile("s_waitcnt vmcnt(8)" ::: "memory"); SBAR();   // LOADB(t+1)->rB1
        WRITEB(1, rB1); SBAR();
        BARRIER(); WAIT_LGKM0();
        __builtin_amdgcn_s_setprio(1); MFMA1(a2, b1); __builtin_amdgcn_s_setprio(0);
        SBAR(); BARRIER();
        // P3
        DS_B3(0, 1, b3); SBAR();
        asm volatile("s_waitcnt vmcnt(4)" ::: "memory"); SBAR();   // STAGEA(t+1) done
        BARRIER(); WAIT_LGKM0();
        __builtin_amdgcn_s_setprio(1); MFMA3(a2, b3); __builtin_amdgcn_s_setprio(0);
        SBAR(); BARRIER();

        // ======== K-step t+1 (buf 1): WRITEB->sB[0] from rB0; LOADB(t+3)->rB1
        // P0
        DS_A(1, 0, a); DS_B1(1, 0, b1); SBAR();
        STAGEA(t + 2, 0); SBAR();
        BARRIER(); WAIT_LGKM0();
        __builtin_amdgcn_s_setprio(1); MFMA1(a, b1); __builtin_amdgcn_s_setprio(0);
        SBAR(); BARRIER();
        // P1
        DS_B3(1, 0, b3); SBAR();
        LOADB(t + 3, rB1); SBAR();
        BARRIER(); WAIT_LGKM0();
        __builtin_amdgcn_s_setprio(1); MFMA3(a, b3); __builtin_amdgcn_s_setprio(0);
        SBAR(); BARRIER();
        // P2
        DS_A(1, 1, a2); DS_B1(1, 1, b1); SBAR();
        asm volatile("s_waitcnt vmcnt(8)" ::: "memory"); SBAR();   // LOADB(t+2)->rB0
        WRITEB(0, rB0); SBAR();
        BARRIER(); WAIT_LGKM0();
        __builtin_amdgcn_s_setprio(1); MFMA1(a2, b1); __builtin_amdgcn_s_setprio(0);
        SBAR(); BARRIER();
        // P3
        DS_B3(1, 1, b3); SBAR();
        asm volatile("s_waitcnt vmcnt(4)" ::: "memory"); SBAR();   // STAGEA(t+2) done
        BARRIER(); WAIT_LGKM0();
        __builtin_amdgcn_s_setprio(1); MFMA3(a2, b3); __builtin_amdgcn_s_setprio(0);
        SBAR(); BARRIER();
    }

    // ======== K-step 14 (buf 0): STAGEA(15); no LOADB; rB1 holds tile 15
    // P0
    DS_A(0, 0, a); DS_B1(0, 0, b1); SBAR();
    STAGEA(15, 1); SBAR();
    BARRIER(); WAIT_LGKM0();
    __builtin_amdgcn_s_setprio(1); MFMA1(a, b1); __builtin_amdgcn_s_setprio(0);
    SBAR(); BARRIER();
    // P1
    DS_B3(0, 0, b3); SBAR();
    BARRIER(); WAIT_LGKM0();
    __builtin_amdgcn_s_setprio(1); MFMA3(a, b3); __builtin_amdgcn_s_setprio(0);
    SBAR(); BARRIER();
    // P2: outstanding = LOADB(15)[4] + STAGEA(15)[4] -> vmcnt(4) drains LOADB(15)
    DS_A(0, 1, a2); DS_B1(0, 1, b1); SBAR();
    asm volatile("s_waitcnt vmcnt(4)" ::: "memory"); SBAR();
    WRITEB(1, rB1); SBAR();
    BARRIER(); WAIT_LGKM0();
    __builtin_amdgcn_s_setprio(1); MFMA1(a2, b1); __builtin_amdgcn_s_setprio(0);
    SBAR(); BARRIER();
    // P3
    DS_B3(0, 1, b3); SBAR();
    asm volatile("s_waitcnt vmcnt(0)" ::: "memory"); SBAR();       // STAGEA(15) done
    BARRIER(); WAIT_LGKM0();
    __builtin_amdgcn_s_setprio(1); MFMA3(a2, b3); __builtin_amdgcn_s_setprio(0);
    SBAR(); BARRIER();

    // ======== K-step 15 (buf 1): plain compute, nothing else outstanding
    DS_A(1, 0, a); DS_B1(1, 0, b1); DS_B3(1, 0, b3);
    WAIT_LGKM0();
    MFMA1(a, b1); MFMA3(a, b3);
    DS_A(1, 1, a2); DS_B1(1, 1, b1); DS_B3(1, 1, b3);
    WAIT_LGKM0();
    MFMA1(a2, b1); MFMA3(a2, b3);

    // ---- epilogue: h = silu(h1) * h3 -> bf16
    const int hcol0 = nt * 64 + wc * 32;
    #pragma unroll
    for (int m = 0; m < 4; ++m) {
        #pragma unroll
        for (int n = 0; n < 2; ++n) {
            #pragma unroll
            for (int i = 0; i < 4; ++i) {
                int row = tok0 + wr * 64 + m * 16 + (lane >> 4) * 4 + i;
                int col = hcol0 + n * 16 + (lane & 15);
                float h1 = acc1[m][n][i];
                float h3 = acc3[m][n][i];
                float sig = 1.0f / (1.0f + __expf(-h1));
                Hout[(size_t)row * HDIM + col] = __float2bfloat16(h1 * sig * h3);
            }
        }
    }
}

// ---------------------------------------------------------------------------
// Kernel 2: out = h W2^T.  (round-11..15 form, near its L2/HBM floor; unchanged)
// A = Hb bf16 via gld_lds; B = W2 fp32->bf16 reg-staged depth-2, write-late.
// ---------------------------------------------------------------------------
__global__ __launch_bounds__(256, 2)
void gemm2_kernel(const __hip_bfloat16* __restrict__ Hin,
                  const float* __restrict__ W2,
                  float* __restrict__ Out)
{
    const int bid = xcd_swizzle_512(blockIdx.x);
    const int e  = bid >> 6;
    const int nt = (bid >> 3) & 7;    // d tile -- major (W2 tile reused)
    const int mt = bid & 7;           // token tile -- fastest (stream Hb)
    const int tok0 = e * TPE + mt * 128;
    const float* __restrict__ We = W2 + (size_t)e * DDIM * HDIM;

    __shared__ __hip_bfloat16 sA[2][128][64];
    __shared__ __hip_bfloat16 sB[2][128][64];

    const int tid  = threadIdx.x;
    const int lane = tid & 63;
    const int wave = tid >> 6;
    const int wr = wave >> 1;
    const int wc = wave & 1;
    const int lr = lane & 15;
    const int sw0 = ((lane >> 4) ^ (lane & 7));

    floatx4 acc[4][4] = {};

    const int srow0 = (tid >> 3);
    const int c8    = (tid & 7) * 8;
    const int dcol  = (tid & 7) * 8;
    const int swcol = ((tid & 7) ^ (srow0 & 7)) * 8;

    float4 rB0[8], rB1[8];

    auto LOADB = [&](int kk, float4* rB) {  // 8 VM ops
        const int k0 = kk * 64;
        #pragma unroll
        for (int j = 0; j < 4; ++j) {
            int row = srow0 + j * 32;
            const float* p = &We[(size_t)(nt * 128 + row) * HDIM + k0 + c8];
            rB[2*j]   = *reinterpret_cast<const float4*>(p);
            rB[2*j+1] = *reinterpret_cast<const float4*>(p + 4);
        }
    };
    auto STAGEA = [&](int kk, int buf) {    // 4 VM ops (gld_lds)
        const int k0 = kk * 64;
        #pragma unroll
        for (int j = 0; j < 4; ++j) {
            int row = srow0 + j * 32;
            gld_lds16(&Hin[(size_t)(tok0 + row) * HDIM + k0 + swcol],
                      &sA[buf][row][dcol]);
        }
    };
    auto WRITEB = [&](int buf, const float4* rB) {
        #pragma unroll
        for (int j = 0; j < 4; ++j) {
            int row = srow0 + j * 32;
            uint4 w;
            w.x = cvt_pk_bf16(rB[2*j].x,   rB[2*j].y);
            w.y = cvt_pk_bf16(rB[2*j].z,   rB[2*j].w);
            w.z = cvt_pk_bf16(rB[2*j+1].x, rB[2*j+1].y);
            w.w = cvt_pk_bf16(rB[2*j+1].z, rB[2*j+1].w);
            *reinterpret_cast<uint4*>(&sB[buf][row][swcol]) = w;
        }
    };
    auto COMPUTE = [&](int buf) {
        #pragma unroll
        for (int ks = 0; ks < 2; ++ks) {
            const int rc = (sw0 ^ (ks << 2)) << 3;
            bf16x8 a[4], b[4];
            #pragma unroll
            for (int m = 0; m < 4; ++m)
                a[m] = *reinterpret_cast<const bf16x8*>(&sA[buf][wr * 64 + m * 16 + lr][rc]);
            #pragma unroll
            for (int n = 0; n < 4; ++n)
                b[n] = *reinterpret_cast<const bf16x8*>(&sB[buf][wc * 64 + n * 16 + lr][rc]);
            #pragma unroll
            for (int m = 0; m < 4; ++m)
                #pragma unroll
                for (int n = 0; n < 4; ++n)
                    acc[m][n] = __builtin_amdgcn_mfma_f32_16x16x32_bf16(a[m], b[n], acc[m][n], 0, 0, 0);
        }
    };

    // ---- prologue
    LOADB(0, rB0);  SBAR();
    STAGEA(0, 0);   SBAR();
    LOADB(1, rB1);  SBAR();
    asm volatile("s_waitcnt vmcnt(12)" ::: "memory");  // LOADB(0) done
    SBAR();
    WRITEB(0, rB0); SBAR();
    asm volatile("s_waitcnt vmcnt(8) lgkmcnt(0)" ::: "memory");
    SBAR();
    __builtin_amdgcn_s_barrier();

    // ---- steady phases 0..5
    for (int t = 0; t < HDIM / 64 - 2; t += 2) {        // t = 0,2,4
        // phase t (buf 0)
        STAGEA(t + 1, 1);   SBAR();
        LOADB(t + 2, rB0);  SBAR();
        COMPUTE(0);
        asm volatile("s_waitcnt vmcnt(12)" ::: "memory");  // LOADB(t+1) -> rB1
        SBAR();
        WRITEB(1, rB1);     SBAR();
        asm volatile("s_waitcnt vmcnt(8) lgkmcnt(0)" ::: "memory");
        SBAR();
        __builtin_amdgcn_s_barrier();
        // phase t+1 (buf 1)
        STAGEA(t + 2, 0);   SBAR();
        LOADB(t + 3, rB1);  SBAR();
        COMPUTE(1);
        asm volatile("s_waitcnt vmcnt(12)" ::: "memory");  // LOADB(t+2) -> rB0
        SBAR();
        WRITEB(0, rB0);     SBAR();
        asm volatile("s_waitcnt vmcnt(8) lgkmcnt(0)" ::: "memory");
        SBAR();
        __builtin_amdgcn_s_barrier();
    }

    // ---- phase 6 (buf 0): leftover LOADB(7) in rB1
    STAGEA(7, 1);   SBAR();
    COMPUTE(0);
    asm volatile("s_waitcnt vmcnt(4)" ::: "memory");   // LOADB(7) done
    SBAR();
    WRITEB(1, rB1); SBAR();
    asm volatile("s_waitcnt vmcnt(0) lgkmcnt(0)" ::: "memory");
    SBAR();
    __builtin_amdgcn_s_barrier();
    // ---- phase 7 (buf 1)
    COMPUTE(1);

    const int dcol0 = nt * 128 + wc * 64;
    #pragma unroll
    for (int m = 0; m < 4; ++m) {
        #pragma unroll
        for (int n = 0; n < 4; ++n) {
            #pragma unroll
            for (int i = 0; i < 4; ++i) {
                int row = tok0 + wr * 64 + m * 16 + (lane >> 4) * 4 + i;
                int col = dcol0 + n * 16 + (lane & 15);
                Out[(size_t)row * DDIM + col] = acc[m][n][i];
            }
        }
    }
}

extern "C" void kernel_launch(void* const* d_in, const int* in_sizes, int n_in,
                              void* d_out, int out_size, void* d_ws, size_t ws_size,
                              hipStream_t stream) {
    const float* X   = (const float*)d_in[0];   // (T, D) fp32
    const float* S   = (const float*)d_in[1];   // (T, D/32) fp32
    const float* W13 = (const float*)d_in[4];   // (E, 2H, D) fp32
    const float* W2  = (const float*)d_in[5];   // (E, D, H) fp32
    float* Out = (float*)d_out;                 // (T, D) fp32

    // workspace: Hb bf16 (T*H) = 8 MiB.
    // Xb (T*D bf16 = 16 MiB) lives in d_out's first half: gemm1 consumes it,
    // then gemm2 overwrites all of d_out with the final fp32 output.
    __hip_bfloat16* Hb = (__hip_bfloat16*)d_ws;
    unsigned short* Xb = (unsigned short*)d_out;

    convert_x_kernel<<<2048, 256, 0, stream>>>(X, S, Xb);
    gemm1_silu_kernel<<<NE * 4 * 8, 512, 0, stream>>>(Xb, W13, Hb);
    gemm2_kernel<<<NE * 8 * 8, 256, 0, stream>>>(Hb, W2, Out);
}